// Round 1
// baseline (181.832 us; speedup 1.0000x reference)
//
#include <hip/hip_runtime.h>

// Problem constants (fixed by setup_inputs in the reference):
//   feature_map: (1, 256, 256, 256) fp32, NHWC
//   rois:        (2000, 5) int32  [batch, x, y, w, h]
//   pool_size:   7
#define FH 256
#define FW 256
#define FC 256
#define POOL 7

// One wave (64 lanes) per output cell (roi, pj, pi); each lane handles 4
// channels via float4. 256 channels / 4 = 64 float4 = exactly one wave, so
// the bilinear coordinate math is wave-uniform (scalar unit) and every
// global access is a fully coalesced 16B/lane transaction.
__global__ __launch_bounds__(256) void roi_pool_kernel(
    const float* __restrict__ fm,
    const int*   __restrict__ rois,
    float*       __restrict__ out,
    int n_rois)
{
    int t = blockIdx.x * blockDim.x + threadIdx.x;
    int total = n_rois * POOL * POOL * (FC / 4);
    if (t >= total) return;

    int lane = t & 63;     // float4 channel-group index within the cell
    int cell = t >> 6;     // (roi, pj, pi)
    int pi   = cell % POOL;
    int tmp  = cell / POOL;
    int pj   = tmp % POOL;
    int roi  = tmp / POOL;

    int rx = rois[roi * 5 + 1];
    int ry = rois[roi * 5 + 2];
    int rw = rois[roi * 5 + 3];
    int rh = rois[roi * 5 + 4];

    // y-axis sample coords (half-pixel centers of a bilinear resize of the
    // crop [ry, ry+rh) to POOL rows), matching the reference exactly.
    float lfh = (float)rh;
    float fy  = ((float)pj + 0.5f) * (lfh / (float)POOL) - 0.5f;
    fy = fminf(fmaxf(fy, 0.0f), lfh - 1.0f);
    int   j0 = (int)floorf(fy);
    int   j1 = min(j0 + 1, rh - 1);
    float wy = fy - (float)j0;
    int   y0 = ry + j0;
    int   y1 = ry + j1;

    // x-axis
    float lfw = (float)rw;
    float fx  = ((float)pi + 0.5f) * (lfw / (float)POOL) - 0.5f;
    fx = fminf(fmaxf(fx, 0.0f), lfw - 1.0f);
    int   i0 = (int)floorf(fx);
    int   i1 = min(i0 + 1, rw - 1);
    float wx = fx - (float)i0;
    int   x0 = rx + i0;
    int   x1 = rx + i1;

    const float4* p00 = (const float4*)(fm + ((size_t)y0 * FW + x0) * FC) + lane;
    const float4* p01 = (const float4*)(fm + ((size_t)y0 * FW + x1) * FC) + lane;
    const float4* p10 = (const float4*)(fm + ((size_t)y1 * FW + x0) * FC) + lane;
    const float4* p11 = (const float4*)(fm + ((size_t)y1 * FW + x1) * FC) + lane;

    float4 a = *p00;
    float4 b = *p01;
    float4 c = *p10;
    float4 d = *p11;

    float owx = 1.0f - wx;
    float owy = 1.0f - wy;

    float4 r;
    {
        float top = a.x * owx + b.x * wx;
        float bot = c.x * owx + d.x * wx;
        r.x = top * owy + bot * wy;
    }
    {
        float top = a.y * owx + b.y * wx;
        float bot = c.y * owx + d.y * wx;
        r.y = top * owy + bot * wy;
    }
    {
        float top = a.z * owx + b.z * wx;
        float bot = c.z * owx + d.z * wx;
        r.z = top * owy + bot * wy;
    }
    {
        float top = a.w * owx + b.w * wx;
        float bot = c.w * owx + d.w * wx;
        r.w = top * owy + bot * wy;
    }

    float4* o = (float4*)(out + (size_t)cell * FC) + lane;
    *o = r;
}

extern "C" void kernel_launch(void* const* d_in, const int* in_sizes, int n_in,
                              void* d_out, int out_size, void* d_ws, size_t ws_size,
                              hipStream_t stream) {
    const float* fm   = (const float*)d_in[0];
    const int*   rois = (const int*)d_in[1];
    // d_in[2] is pool_size (==7), fixed by the problem; hardcoded as POOL.
    float* out = (float*)d_out;

    int n_rois = in_sizes[1] / 5;
    int total  = n_rois * POOL * POOL * (FC / 4);   // one thread per float4
    int block  = 256;
    int grid   = (total + block - 1) / block;

    roi_pool_kernel<<<grid, block, 0, stream>>>(fm, rois, out, n_rois);
}